// Round 13
// baseline (446.532 us; speedup 1.0000x reference)
//
#include <hip/hip_runtime.h>
#include <cstdint>
#include <cstddef>

// Problem constants (fixed by reference file)
#define NB_N 100000
#define E_N  131072
#define T_N  16384
#define D_N  512
#define NCLS 40
#define NTILES 782          // ceil(100000/128) upper bound; real tile count = ceil(cnt/128)
#define CAPR 12             // legacy-path register z-cache edges/target

typedef unsigned short u16;
typedef unsigned int   u32;
typedef __attribute__((ext_vector_type(8))) short  short8;   // 8 bf16 (4 VGPRs)
typedef __attribute__((ext_vector_type(4))) float  floatx4;  // MFMA accumulator

// ---------- bf16 helpers (manual, RNE) ----------
__device__ __forceinline__ u16 f2bf(float f) {
  u32 u = __float_as_uint(f);
  return (u16)((u + 0x7fffu + ((u >> 16) & 1u)) >> 16);
}
__device__ __forceinline__ void unpack8(uint4 z, float* f) {
  f[0] = __uint_as_float(z.x << 16);
  f[1] = __uint_as_float(z.x & 0xffff0000u);
  f[2] = __uint_as_float(z.y << 16);
  f[3] = __uint_as_float(z.y & 0xffff0000u);
  f[4] = __uint_as_float(z.z << 16);
  f[5] = __uint_as_float(z.z & 0xffff0000u);
  f[6] = __uint_as_float(z.w << 16);
  f[7] = __uint_as_float(z.w & 0xffff0000u);
}
__device__ __forceinline__ void gload_lds16(const void* g, void* s) {
  __builtin_amdgcn_global_load_lds(
      (const __attribute__((address_space(1))) unsigned int*)g,
      (__attribute__((address_space(3))) unsigned int*)s, 16, 0, 0);
}
// packed f32x2 -> bf16x2 (RNE), hw instruction; bit-identical to f2bf on finite vals
__device__ __forceinline__ u32 cvtpk_bf16(float lo, float hi) {
  u32 r;
  asm("v_cvt_pk_bf16_f32 %0, %1, %2" : "=v"(r) : "v"(lo), "v"(hi));
  return r;
}

// ---------- kernel P: fused prep (4 independent roles, grid-partitioned).
//            blocks 0..63:    LDS-tiled transpose pca_w (512,512) f32 -> Bt bf16
//            blocks 64..191:  conv mlp_w (512,40) -> Bt2 (64,512) bf16, zero-pad
//            blocks 192..703: CSR offsets from sorted row_idx
//            blocks 704..1094: zero row-mask (+ cnt=0) for the compaction pass ----------
__global__ void prep(const float* __restrict__ w, const float* __restrict__ w2,
                     const int* __restrict__ rowi,
                     u16* __restrict__ Bt, u16* __restrict__ Bt2,
                     int* __restrict__ offs, int* __restrict__ mask,
                     int* __restrict__ cnt) {
  const int b = blockIdx.x, tid = threadIdx.x;
  if (b < 64) {
    __shared__ float T[64][65];           // +1 pad: conflict-free transposed reads
    const int tr = b >> 3, tc = b & 7;    // k-tile, n-tile (64x64)
    const int c0 = tid & 63;
    const int r0 = tid >> 6;              // 0..3
#pragma unroll
    for (int i = 0; i < 16; ++i) {
      int kl = r0 * 16 + i;
      T[kl][c0] = w[(size_t)(tr * 64 + kl) * 512 + tc * 64 + c0];
    }
    __syncthreads();
#pragma unroll
    for (int i = 0; i < 16; ++i) {
      int nl = r0 + i * 4;
      Bt[(size_t)(tc * 64 + nl) * 512 + tr * 64 + c0] = f2bf(T[c0][nl]);
    }
  } else if (b < 192) {
    int i = (b - 64) * 256 + tid;         // 64*512 elements, i = n*512+k
    int n = i >> 9, k = i & 511;
    Bt2[i] = (n < NCLS) ? f2bf(w2[k * NCLS + n]) : (u16)0;
  } else if (b < 704) {
    int e = (b - 192) * 256 + tid;
    if (e >= E_N) return;
    int r  = rowi[e];
    int rp = (e == 0) ? -1 : rowi[e - 1];
    for (int t = rp + 1; t <= r; ++t) offs[t] = e;
    if (e == E_N - 1)
      for (int t = r + 1; t <= T_N; ++t) offs[t] = E_N;
  } else {
    int i = (b - 704) * 256 + tid;
    if (i < NB_N) mask[i] = 0;
    if (b == 704 && tid == 0) *cnt = 0;
  }
}

// ---------- kernel M: mark referenced rows (races benign: all write 1) ----------
__global__ void mark_rows(const int* __restrict__ coli, int* __restrict__ mask) {
  int e = blockIdx.x * 256 + threadIdx.x;
  if (e < E_N) mask[coli[e]] = 1;
}

// ---------- kernel C: compact referenced rows -> rlist (pos->row), cmap (row->pos).
//            Order nondeterministic (atomic); final output is order-invariant
//            since each row's GEMM+l2norm is computed independently. ----------
__global__ void compact_rows(const int* __restrict__ mask, int* __restrict__ cnt,
                             int* __restrict__ cmap, int* __restrict__ rlist) {
  int i = blockIdx.x * 256 + threadIdx.x;
  if (i < NB_N && mask[i]) {
    int pos = atomicAdd(cnt, 1);          // compiler coalesces to per-wave atomic
    cmap[i] = pos;
    rlist[pos] = i;
  }
}

// ---------- kernel 3: bf16 MFMA GEMM x = relu(x_nb @ pca_w + b), per-capsule l2norm,
//            writes xn bf16 COMPACTED to the ~73K referenced rows.
//            R16 = R12 structure (PROVEN: 128x128, 256 thr, BK=64, 3 blocks/CU,
//            reg-staged A + dbuf DMA B, counted-vmcnt 2-barrier schedule) with
//            rlist-indexed A rows: only rows appearing in col_idx are computed
//            (E=131072 uniform draws over 100K -> ~73.1K unique, -27% m-work).
//            Per-thread row indices hoisted out of the k-loop (4 loads, once). ----------
__global__ __launch_bounds__(256, 3) void gemm_pca(
    const float* __restrict__ A,    // x_nb (NB,512) f32
    const u16*   __restrict__ Bt,   // (512,512) bf16, n-major (pre-transposed)
    const float* __restrict__ bias, // (512,)
    u16*         __restrict__ xn,   // (cnt,512) bf16, normalized, compacted
    const int*   __restrict__ rlist,// pos -> original row
    const int*   __restrict__ cntp) {
  __shared__ u16 SMEM[24576];       // 48 KB: As 128x64 (16KB) | Bs dbuf 2x 128x64 (32KB)
  u16* As = SMEM;
  u16* Bs = SMEM + 8192;            // buffer b at Bs + b*8192
  const int tid  = threadIdx.x;
  const int wid  = tid >> 6, lane = tid & 63;
  const int quad = lane >> 4, l16 = lane & 15;
  // XCD-grouped decode: b = 32g + 8n + mlow -> mt = 8g+mlow, n in {0..3}.
  const int b  = blockIdx.x;
  const int mt = (b & 7) | ((b >> 5) << 3);
  if (mt >= NTILES) return;
  const int cnt = *cntp;            // ~73K (scalar load, wave-uniform)
  const int m0 = mt * 128;
  if (m0 >= cnt) return;            // tile fully past the compacted range
  const int n0 = ((b >> 3) & 3) * 128;
  const int wm = (wid >> 1) * 64;
  const int wn = (wid & 1) * 64;
  const int sw = l16 & 7;           // per-lane chunk swizzle for frag reads

  // per-thread A-row sources (hoisted: row constant across k-steps)
  const float* asrc[4];
#pragma unroll
  for (int j = 0; j < 4; ++j) {
    int row = (j * 256 + tid) >> 3;
    int gm = m0 + row;
    if (gm > cnt - 1) gm = cnt - 1;       // clamp: exact vmcnt, rows never stored
    asrc[j] = A + (size_t)rlist[gm] * 512;
  }

  floatx4 acc[4][4];
#pragma unroll
  for (int i = 0; i < 4; ++i)
#pragma unroll
    for (int j = 0; j < 4; ++j) acc[i][j] = (floatx4){0.f, 0.f, 0.f, 0.f};

  float4 pa0[4], pa1[4];            // in-flight A regs: 4 units x 2 float4 (8 loads)

  auto issueA = [&](int k0) {
#pragma unroll
    for (int j = 0; j < 4; ++j) {
      int ci = j * 256 + tid;
      int kc = ci & 7;
      const float* src = asrc[j] + k0 + kc * 8;
      pa0[j] = *(const float4*)(src);
      pa1[j] = *(const float4*)(src + 4);
    }
  };
  auto writeA = [&]() {
#pragma unroll
    for (int j = 0; j < 4; ++j) {
      int ci = j * 256 + tid;
      int row = ci >> 3, kc = ci & 7;
      uint4 pk;
      pk.x = cvtpk_bf16(pa0[j].x, pa0[j].y);
      pk.y = cvtpk_bf16(pa0[j].z, pa0[j].w);
      pk.z = cvtpk_bf16(pa1[j].x, pa1[j].y);
      pk.w = cvtpk_bf16(pa1[j].z, pa1[j].w);
      int dc = kc ^ (row & 7);                // dest-side swizzle
      *(uint4*)(&As[(size_t)(row * 8 + dc) * 8]) = pk;
    }
  };
  auto issueB = [&](int k0, u16* dstB) {
#pragma unroll
    for (int j = 0; j < 4; ++j) {
      int ci  = j * 256 + wid * 64 + lane;    // 1024 chunks
      int row = ci >> 3;
      int kcs = (lane & 7) ^ ((lane >> 3) & 7);
      gload_lds16(Bt + (size_t)(n0 + row) * 512 + k0 + kcs * 8,
                  &dstB[(size_t)(j * 256 + wid * 64) * 8]);
    }
  };

  // ---- prologue: A0, B0, B1 staged; A1 in flight ----
  issueA(0);                          // A0: 8 loads
  issueB(0, Bs);                      // B0 -> slot 0 (4 DMA)
  issueB(64, Bs + 8192);              // B1 -> slot 1 (4 DMA)
  writeA();                           // implicit vmcnt(8): A0 done; B0,B1 in flight
  issueA(64);                         // A1: 8 loads
  asm volatile("s_waitcnt vmcnt(12) lgkmcnt(0)" ::: "memory");  // drain B0; keep B1+A1
  __builtin_amdgcn_s_barrier();
  __builtin_amdgcn_sched_barrier(0);

  // ---- main loop: 8 k-steps, 2 barriers/step; B issued 2 steps ahead ----
#pragma unroll
  for (int s = 0; s < 8; ++s) {
    const int cs = s & 1;
    const u16* Bsc = Bs + cs * 8192;
    // compute step s (reads As + Bsc)
#pragma unroll
    for (int kk = 0; kk < 64; kk += 32) {
      short8 af[4], bf[4];
#pragma unroll
      for (int mi = 0; mi < 4; ++mi) {
        int c = (kk >> 3) + quad;
        af[mi] = *(const short8*)(&As[(wm + mi * 16 + l16) * 64 + ((c ^ sw) << 3)]);
      }
#pragma unroll
      for (int ni = 0; ni < 4; ++ni) {
        int c = (kk >> 3) + quad;
        bf[ni] = *(const short8*)(&Bsc[(wn + ni * 16 + l16) * 64 + ((c ^ sw) << 3)]);
      }
#pragma unroll
      for (int mi = 0; mi < 4; ++mi)
#pragma unroll
        for (int ni = 0; ni < 4; ++ni)
          acc[mi][ni] = __builtin_amdgcn_mfma_f32_16x16x32_bf16(af[mi], bf[ni],
                                                                acc[mi][ni], 0, 0, 0);
    }
    // barrier 1: all waves done READING As + Bs[cs] (slot cs now free)
    __builtin_amdgcn_s_barrier();
    __builtin_amdgcn_sched_barrier(0);
    if (s + 1 < 8) {
      if (s + 2 < 8) issueB((s + 2) * 64, Bs + cs * 8192);  // slot (s+2)&1 == cs
      writeA();                       // implicit wait: A(s+1) done -> B(s+1) (older) done
      if (s + 2 < 8) {
        issueA((s + 2) * 64);         // refill A regs (8 loads)
        asm volatile("s_waitcnt vmcnt(12) lgkmcnt(0)" ::: "memory");  // keep B(s+2)+A(s+2)
      } else {
        asm volatile("s_waitcnt vmcnt(0) lgkmcnt(0)" ::: "memory");   // tail: drain all
      }
      __builtin_amdgcn_s_barrier();   // barrier 2: As written + B(s+1) resident
      __builtin_amdgcn_sched_barrier(0);
    }
  }
  __syncthreads();                    // all compute done before Os overwrites SMEM

  // epilogue: +bias, relu, per-capsule (64-col) l2norm -> LDS tile -> full-line stores
  u16* Os = SMEM;                     // 128x128 u16 = 32 KB (As/Bs dead)
#pragma unroll
  for (int mi = 0; mi < 4; ++mi) {
#pragma unroll
    for (int r = 0; r < 4; ++r) {
      int lrow = wm + mi * 16 + quad * 4 + r;
      float v[4];
      float ss = 0.f;
#pragma unroll
      for (int ni = 0; ni < 4; ++ni) {
        int n  = n0 + wn + ni * 16 + l16;
        float x = acc[mi][ni][r] + bias[n];
        x = fmaxf(x, 0.f);
        v[ni] = x;
        ss += x * x;
      }
      ss += __shfl_xor(ss, 1);
      ss += __shfl_xor(ss, 2);
      ss += __shfl_xor(ss, 4);
      ss += __shfl_xor(ss, 8);
      float sc = 1.f / fmaxf(sqrtf(ss), 1e-12f);
#pragma unroll
      for (int ni = 0; ni < 4; ++ni)
        Os[lrow * 128 + wn + ni * 16 + l16] = f2bf(v[ni] * sc);
    }
  }
  __syncthreads();
#pragma unroll
  for (int c8 = 0; c8 < 8; ++c8) {    // 2048 16B-chunks, 8 per thread
    int idx = c8 * 256 + tid;
    int row = idx >> 4, chk = idx & 15;
    int gm = m0 + row;
    if (gm < cnt) {
      uint4 val = *(const uint4*)(&Os[row * 128 + chk * 8]);
      *(uint4*)(xn + (size_t)gm * 512 + n0 + chk * 8) = val;
    }
  }
}

// ---------- fast-path helpers for kernel 4 ----------
// matvec in coefficient space: e_i = sum_j G[i][j] * w[j], rows i0 / i0+8 per lane.
__device__ __forceinline__ void matvec16(const float (&g0)[16], const float (&g1)[16],
                                         float w0, float w1, int base,
                                         float& e0, float& e1) {
  e0 = 0.f; e1 = 0.f;
#pragma unroll
  for (int j = 0; j < 8; ++j) {
    float wj = __shfl(w0, base | j);
    e0 += g0[j] * wj;
    e1 += g1[j] * wj;
  }
#pragma unroll
  for (int j = 0; j < 8; ++j) {
    float wj = __shfl(w1, base | j);
    e0 += g0[8 + j] * wj;
    e1 += g1[8 + j] * wj;
  }
}

// segment softmax over edges of one capsule: values d0 (edge i0), d1 (edge i0+8)
__device__ __forceinline__ void segsm2(float& d0, float& d1, bool v0, bool v1) {
  float m = fmaxf(v0 ? d0 : -INFINITY, v1 ? d1 : -INFINITY);
  m = fmaxf(m, __shfl_xor(m, 1));
  m = fmaxf(m, __shfl_xor(m, 2));
  m = fmaxf(m, __shfl_xor(m, 4));
  float e0 = v0 ? expf(d0 - m) : 0.f;
  float e1 = v1 ? expf(d1 - m) : 0.f;
  float s = e0 + e1;
  s += __shfl_xor(s, 1);
  s += __shfl_xor(s, 2);
  s += __shfl_xor(s, 4);
  float inv = 1.f / s;
  d0 = e0 * inv;
  d1 = e1 * inv;
}

// ---------- kernel 4: ALL routing (init + 3 rounds), one target per wave.
//            R16: col indices translated through cmap (xn is compacted).
//            In-wave ppr segment softmax (no ppr_sm kernel / pprn buffer).
//            FAST PATH (deg<=16): Gram via MFMA, routing in coefficient space.
//            LEGACY PATH (deg>16): edge loop. ----------
__global__ __launch_bounds__(128, 4) void fused_all(
    const u16* __restrict__ xn, const int* __restrict__ coli,
    const int* __restrict__ offs, const float* __restrict__ ppr,
    u16* __restrict__ ub, const int* __restrict__ cmap) {
  __shared__ __align__(16) float Glds[2][8 * 260];
  const int lane = threadIdx.x & 63;
  const int wv = threadIdx.x >> 6;
  const int t = blockIdx.x * 2 + wv;
  const int s = offs[t], en = offs[t + 1];
  int deg = en - s;
  if (deg > 64) deg = 64;           // Poisson(8): max over 16k targets ~27

  int   mycol = (lane < deg) ? cmap[coli[s + lane]] : 0;   // compact index
  float praw  = (lane < deg) ? ppr[s + lane] : 0.f;

  // in-wave segment softmax of raw ppr over lanes [0,deg)
  float myppr;
  {
    float v = (lane < deg) ? praw : -INFINITY;
    float m = v;
    m = fmaxf(m, __shfl_xor(m, 1));
    m = fmaxf(m, __shfl_xor(m, 2));
    m = fmaxf(m, __shfl_xor(m, 4));
    m = fmaxf(m, __shfl_xor(m, 8));
    m = fmaxf(m, __shfl_xor(m, 16));
    m = fmaxf(m, __shfl_xor(m, 32));
    float e = (lane < deg) ? expf(praw - m) : 0.f;
    float ss = e;
    ss += __shfl_xor(ss, 1);
    ss += __shfl_xor(ss, 2);
    ss += __shfl_xor(ss, 4);
    ss += __shfl_xor(ss, 8);
    ss += __shfl_xor(ss, 16);
    ss += __shfl_xor(ss, 32);
    myppr = e / ss;                 // deg=0 -> NaN, but uf-loops skip -> unused
  }

  float uf[8] = {0.f, 0.f, 0.f, 0.f, 0.f, 0.f, 0.f, 0.f};

  if (deg <= 16) {
    // ================= fast path =================
    float* G = Glds[wv];
    const int esrc = lane & 15, kq = lane >> 4;
    int ce = __shfl(mycol, esrc);
    const u16* zb = xn + (size_t)ce * 512 + kq * 8;
    floatx4 gram[8];
#pragma unroll
    for (int c = 0; c < 8; ++c) {
      short8 f0 = *(const short8*)(zb + c * 64);
      short8 f1 = *(const short8*)(zb + c * 64 + 32);
      floatx4 gg = (floatx4){0.f, 0.f, 0.f, 0.f};
      gg = __builtin_amdgcn_mfma_f32_16x16x32_bf16(f0, f0, gg, 0, 0, 0);
      gg = __builtin_amdgcn_mfma_f32_16x16x32_bf16(f1, f1, gg, 0, 0, 0);
      gram[c] = gg;
    }
#pragma unroll
    for (int c = 0; c < 8; ++c)
      *(float4*)&G[c * 260 + esrc * 16 + kq * 4] = *(float4*)&gram[c];
    const int cc = lane >> 3, i0 = lane & 7;
    const int base = lane & 56;
    float g0[16], g1[16];
    {
      const float* r0 = &G[cc * 260 + i0 * 16];
      const float* r1 = &G[cc * 260 + (i0 + 8) * 16];
#pragma unroll
      for (int ch = 0; ch < 4; ++ch) {
        float4 a = *(const float4*)(r0 + ch * 4);
        float4 b = *(const float4*)(r1 + ch * 4);
        g0[ch * 4 + 0] = a.x; g0[ch * 4 + 1] = a.y;
        g0[ch * 4 + 2] = a.z; g0[ch * 4 + 3] = a.w;
        g1[ch * 4 + 0] = b.x; g1[ch * 4 + 1] = b.y;
        g1[ch * 4 + 2] = b.z; g1[ch * 4 + 3] = b.w;
      }
    }
    const bool v0 = i0 < deg, v1 = (i0 + 8) < deg;
    float pr0 = __shfl(myppr, i0);
    float pr1 = __shfl(myppr, i0 + 8);

    float d0, d1;
    matvec16(g0, g1, pr0, pr1, base, d0, d1);

    float w0 = 0.f, w1 = 0.f;
#pragma unroll
    for (int it = 0; it < 3; ++it) {
      segsm2(d0, d1, v0, v1);
      d0 = 0.5f * d0 + 0.5f * pr0;
      d1 = 0.5f * d1 + 0.5f * pr1;
      segsm2(d0, d1, v0, v1);
      w0 = d0; w1 = d1;
      if (it < 2) {
        float e0, e1;
        matvec16(g0, g1, w0, w1, base, e0, e1);
        float nv = w0 * e0 + w1 * e1;
        nv += __shfl_xor(nv, 1);
        nv += __shfl_xor(nv, 2);
        nv += __shfl_xor(nv, 4);
        float invn = 1.f / fmaxf(sqrtf(nv), 1e-12f);
        d0 = e0 * invn;
        d1 = e1 * invn;
      }
    }

#pragma unroll
    for (int j = 0; j < 16; ++j) {
      if (j < deg) {
        float wj = __shfl((j < 8) ? w0 : w1, base | (j & 7));
        int cj = __shfl(mycol, j);
        uint4 zz = *(const uint4*)(xn + (size_t)cj * 512 + lane * 8);
        float zf[8];
        unpack8(zz, zf);
#pragma unroll
        for (int q = 0; q < 8; ++q) uf[q] += wj * zf[q];
      }
    }
  } else {
    // ================= legacy path (deg > 16, ~0.4% of targets) =================
    const int cap = lane >> 3;
    const int slot = lane >> 3;

    uint4 zreg[CAPR];
#pragma unroll
    for (int j = 0; j < CAPR; ++j) {
      if (j < deg) {
        int c = __shfl(mycol, j);
        zreg[j] = *(const uint4*)(xn + (size_t)c * 512 + lane * 8);
      }
    }

#pragma unroll
    for (int j = 0; j < CAPR; ++j) {
      if (j < deg) {
        float w = __shfl(myppr, j);
        float zf[8];
        unpack8(zreg[j], zf);
#pragma unroll
        for (int q = 0; q < 8; ++q) uf[q] += w * zf[q];
      }
    }
    for (int j = CAPR; j < deg; ++j) {
      float w = __shfl(myppr, j);
      int c = __shfl(mycol, j);
      uint4 zz = *(const uint4*)(xn + (size_t)c * 512 + lane * 8);
      float zf[8];
      unpack8(zz, zf);
#pragma unroll
      for (int q = 0; q < 8; ++q) uf[q] += w * zf[q];
    }

    float Preg[8];

    for (int it = 0; it < 3; ++it) {
#pragma unroll
      for (int j = 0; j < CAPR; ++j) {
        if (j < deg) {
          float zf[8];
          unpack8(zreg[j], zf);
          float d = uf[0]*zf[0] + uf[1]*zf[1] + uf[2]*zf[2] + uf[3]*zf[3] +
                    uf[4]*zf[4] + uf[5]*zf[5] + uf[6]*zf[6] + uf[7]*zf[7];
          d += __shfl_xor(d, 1);
          d += __shfl_xor(d, 2);
          d += __shfl_xor(d, 4);
          float dc = __shfl(d, (lane & 7) << 3);
          if (slot == (j & 7)) Preg[j >> 3] = dc;
        }
      }
      for (int j = CAPR; j < deg; ++j) {
        int c = __shfl(mycol, j);
        uint4 zz = *(const uint4*)(xn + (size_t)c * 512 + lane * 8);
        float zf[8];
        unpack8(zz, zf);
        float d = uf[0]*zf[0] + uf[1]*zf[1] + uf[2]*zf[2] + uf[3]*zf[3] +
                  uf[4]*zf[4] + uf[5]*zf[5] + uf[6]*zf[6] + uf[7]*zf[7];
        d += __shfl_xor(d, 1);
        d += __shfl_xor(d, 2);
        d += __shfl_xor(d, 4);
        float dc = __shfl(d, (lane & 7) << 3);
        if (slot == (j & 7)) {
          int hi = j >> 3;
          if      (hi == 1) Preg[1] = dc;
          else if (hi == 2) Preg[2] = dc;
          else if (hi == 3) Preg[3] = dc;
          else if (hi == 4) Preg[4] = dc;
          else if (hi == 5) Preg[5] = dc;
          else if (hi == 6) Preg[6] = dc;
          else if (hi == 7) Preg[7] = dc;
        }
      }

      {
        float m1 = -INFINITY;
#pragma unroll
        for (int i = 0; i < 8; ++i)
          m1 = (slot + 8*i < deg) ? fmaxf(m1, Preg[i]) : m1;
        m1 = fmaxf(m1, __shfl_xor(m1, 8));
        m1 = fmaxf(m1, __shfl_xor(m1, 16));
        m1 = fmaxf(m1, __shfl_xor(m1, 32));
        float s1 = 0.f;
#pragma unroll
        for (int i = 0; i < 8; ++i)
          s1 += (slot + 8*i < deg) ? expf(Preg[i] - m1) : 0.f;
        s1 += __shfl_xor(s1, 8);
        s1 += __shfl_xor(s1, 16);
        s1 += __shfl_xor(s1, 32);
        float inv1 = 1.f / s1;
        float m2 = -INFINITY;
#pragma unroll
        for (int i = 0; i < 8; ++i) {
          int j = slot + 8*i;
          if (j < deg) {
            float pj = __shfl(myppr, j);
            float v = 0.5f * expf(Preg[i] - m1) * inv1 + 0.5f * pj;
            Preg[i] = v;
            m2 = fmaxf(m2, v);
          }
        }
        m2 = fmaxf(m2, __shfl_xor(m2, 8));
        m2 = fmaxf(m2, __shfl_xor(m2, 16));
        m2 = fmaxf(m2, __shfl_xor(m2, 32));
        float s2 = 0.f;
#pragma unroll
        for (int i = 0; i < 8; ++i)
          s2 += (slot + 8*i < deg) ? expf(Preg[i] - m2) : 0.f;
        s2 += __shfl_xor(s2, 8);
        s2 += __shfl_xor(s2, 16);
        s2 += __shfl_xor(s2, 32);
        float inv2 = 1.f / s2;
#pragma unroll
        for (int i = 0; i < 8; ++i)
          if (slot + 8*i < deg) Preg[i] = expf(Preg[i] - m2) * inv2;
      }

      float acc[8] = {0.f, 0.f, 0.f, 0.f, 0.f, 0.f, 0.f, 0.f};
#pragma unroll
      for (int j = 0; j < CAPR; ++j) {
        if (j < deg) {
          float w = __shfl(Preg[j >> 3], ((j & 7) << 3) | cap);
          float zf[8];
          unpack8(zreg[j], zf);
#pragma unroll
          for (int q = 0; q < 8; ++q) acc[q] += w * zf[q];
        }
      }
      for (int j = CAPR; j < deg; ++j) {
        int hi = j >> 3;
        float pr = Preg[1];
        if      (hi == 2) pr = Preg[2];
        else if (hi == 3) pr = Preg[3];
        else if (hi == 4) pr = Preg[4];
        else if (hi == 5) pr = Preg[5];
        else if (hi == 6) pr = Preg[6];
        else if (hi == 7) pr = Preg[7];
        float w = __shfl(pr, ((j & 7) << 3) | cap);
        int c = __shfl(mycol, j);
        uint4 zz = *(const uint4*)(xn + (size_t)c * 512 + lane * 8);
        float zf[8];
        unpack8(zz, zf);
#pragma unroll
        for (int q = 0; q < 8; ++q) acc[q] += w * zf[q];
      }
      if (it < 2) {
        float ss = 0.f;
#pragma unroll
        for (int q = 0; q < 8; ++q) ss += acc[q] * acc[q];
        ss += __shfl_xor(ss, 1);
        ss += __shfl_xor(ss, 2);
        ss += __shfl_xor(ss, 4);
        float sc = 1.f / fmaxf(sqrtf(ss), 1e-12f);
#pragma unroll
        for (int q = 0; q < 8; ++q) acc[q] *= sc;
      }
#pragma unroll
      for (int q = 0; q < 8; ++q) uf[q] = acc[q];
    }
  }

  // output: ub = bf16(relu(u)) for the MLP GEMM
  uint4 pk;
  pk.x = (u32)f2bf(fmaxf(uf[0], 0.f)) | ((u32)f2bf(fmaxf(uf[1], 0.f)) << 16);
  pk.y = (u32)f2bf(fmaxf(uf[2], 0.f)) | ((u32)f2bf(fmaxf(uf[3], 0.f)) << 16);
  pk.z = (u32)f2bf(fmaxf(uf[4], 0.f)) | ((u32)f2bf(fmaxf(uf[5], 0.f)) << 16);
  pk.w = (u32)f2bf(fmaxf(uf[6], 0.f)) | ((u32)f2bf(fmaxf(uf[7], 0.f)) << 16);
  *(uint4*)(ub + (size_t)t * 512 + lane * 8) = pk;
}

// ---------- kernel 5: logits = ub @ Bt2^T + mb; fused log_softmax epilogue. ----------
__global__ __launch_bounds__(256) void mlp_gemm(
    const u16* __restrict__ ub, const u16* __restrict__ Bt2,
    const float* __restrict__ mb, float* __restrict__ out) {
  const int wid = threadIdx.x >> 6, lane = threadIdx.x & 63;
  const int quad = lane >> 4, l16 = lane & 15;
  const int m0 = blockIdx.x * 64 + wid * 16;

  floatx4 acc[4];
#pragma unroll
  for (int ni = 0; ni < 4; ++ni) acc[ni] = (floatx4){0.f, 0.f, 0.f, 0.f};

#pragma unroll 4
  for (int kk = 0; kk < 512; kk += 32) {
    short8 af = *(const short8*)(ub + (size_t)(m0 + l16) * 512 + kk + quad * 8);
#pragma unroll
    for (int ni = 0; ni < 4; ++ni) {
      short8 bf = *(const short8*)(Bt2 + (size_t)(ni * 16 + l16) * 512 + kk + quad * 8);
      acc[ni] = __builtin_amdgcn_mfma_f32_16x16x32_bf16(af, bf, acc[ni], 0, 0, 0);
    }
  }

#pragma unroll
  for (int r = 0; r < 4; ++r) {
    int t = m0 + quad * 4 + r;
    float v[4];
    float mx = -INFINITY;
#pragma unroll
    for (int ni = 0; ni < 4; ++ni) {
      int c = ni * 16 + l16;
      float lg = (c < NCLS) ? (acc[ni][r] + mb[c]) : -INFINITY;
      v[ni] = lg;
      mx = fmaxf(mx, lg);
    }
    mx = fmaxf(mx, __shfl_xor(mx, 1));
    mx = fmaxf(mx, __shfl_xor(mx, 2));
    mx = fmaxf(mx, __shfl_xor(mx, 4));
    mx = fmaxf(mx, __shfl_xor(mx, 8));
    float se = 0.f;
#pragma unroll
    for (int ni = 0; ni < 4; ++ni) {
      int c = ni * 16 + l16;
      if (c < NCLS) se += expf(v[ni] - mx);
    }
    se += __shfl_xor(se, 1);
    se += __shfl_xor(se, 2);
    se += __shfl_xor(se, 4);
    se += __shfl_xor(se, 8);
    float lse = mx + logf(se);
#pragma unroll
    for (int ni = 0; ni < 4; ++ni) {
      int c = ni * 16 + l16;
      if (c < NCLS) out[(size_t)t * NCLS + c] = v[ni] - lse;
    }
  }
}

// ---------- launch ----------
extern "C" void kernel_launch(void* const* d_in, const int* in_sizes, int n_in,
                              void* d_out, int out_size, void* d_ws, size_t ws_size,
                              hipStream_t stream) {
  const float* x_nb  = (const float*)d_in[0];
  const float* ppr   = (const float*)d_in[1];
  const float* pca_w = (const float*)d_in[2];
  const float* pca_b = (const float*)d_in[3];
  const float* mlp_w = (const float*)d_in[4];
  const float* mlp_b = (const float*)d_in[5];
  const int* row_idx = (const int*)d_in[6];
  const int* col_idx = (const int*)d_in[7];
  float* out = (float*)d_out;

  char* ws = (char*)d_ws;
  const size_t OFF_BT    = 0;                                 // 512 KB
  const size_t OFF_BT2   = 512 * 1024;                        // 64 KB
  const size_t OFF_OFFS  = 640 * 1024;                        // (T+1)*4 = 66 KB
  const size_t OFF_MASK  = 768 * 1024;                        // NB*4 = 400 KB
  const size_t OFF_RLIST = 1280 * 1024;                       // NB*4
  const size_t OFF_CMAP  = 1792 * 1024;                       // NB*4
  const size_t OFF_CNT   = 2304 * 1024;                       // 4 B
  const size_t OFF_XN    = 2368 * 1024;                       // cnt*512*2 <= 102.4 MB
  const size_t OFF_UB    = OFF_XN + (size_t)NB_N * 512 * 2;   // T*512*2 = 16.8 MB
  u16*   Bt    = (u16*)(ws + OFF_BT);
  u16*   Bt2   = (u16*)(ws + OFF_BT2);
  int*   offs  = (int*)(ws + OFF_OFFS);
  int*   mask  = (int*)(ws + OFF_MASK);
  int*   rlist = (int*)(ws + OFF_RLIST);
  int*   cmap  = (int*)(ws + OFF_CMAP);
  int*   cnt   = (int*)(ws + OFF_CNT);
  u16*   xn    = (u16*)(ws + OFF_XN);
  u16*   ub    = (u16*)(ws + OFF_UB);

  // prep: Bt transpose (64) | Bt2 (128) | offs (512) | mask/cnt zero (391)
  prep<<<1095, 256, 0, stream>>>(pca_w, mlp_w, row_idx, Bt, Bt2, offs, mask, cnt);
  mark_rows<<<512, 256, 0, stream>>>(col_idx, mask);
  compact_rows<<<391, 256, 0, stream>>>(mask, cnt, cmap, rlist);

  // 98 groups of 32 blocks; blocks past ceil(cnt/128) tiles exit immediately
  gemm_pca<<<98 * 32, 256, 0, stream>>>(x_nb, Bt, pca_b, xn, rlist, cnt);

  fused_all<<<T_N / 2, 128, 0, stream>>>(xn, col_idx, offs, ppr, ub, cmap);

  mlp_gemm<<<256, 256, 0, stream>>>(ub, Bt2, mlp_b, out);
}